// Round 12
// baseline (1066.734 us; speedup 1.0000x reference)
//
#include <hip/hip_runtime.h>
#include <hip/hip_bf16.h>
#include <stdint.h>

// ---------------- problem constants ----------------
#define M_DIM 8192            // B*S = 4*2048
#define N_DIM 11008
#define K_DIM 4096
#define NT32 128              // K-tiles of 32

typedef unsigned short ushort_t;
typedef __attribute__((ext_vector_type(8)))  short  short8;
typedef __attribute__((ext_vector_type(8)))  __bf16 bf16x8;
typedef __attribute__((ext_vector_type(4)))  float  f32x4;
typedef __attribute__((ext_vector_type(16))) float  f32x16;

__device__ __forceinline__ ushort_t f2bf(float f){
  uint32_t u = __builtin_bit_cast(uint32_t, f);
  u += 0x7FFFu + ((u >> 16) & 1u);
  return (ushort_t)(u >> 16);
}

__device__ __forceinline__ void gll16(const void* g, void* l){
  __builtin_amdgcn_global_load_lds(
      (const __attribute__((address_space(1))) void*)g,
      (__attribute__((address_space(3))) void*)l,
      16, 0, 0);
}

// ---------------- pre-pass converts ----------------
__global__ void cvt_x_kernel(const float* __restrict__ x, ushort_t* __restrict__ xb){
  const int TOT = 33554432/8;
  for (int c = blockIdx.x*blockDim.x + threadIdx.x; c < TOT; c += gridDim.x*blockDim.x){
    size_t i = (size_t)c*8;
    float4 v0 = *(const float4*)(x+i);
    float4 v1 = *(const float4*)(x+i+4);
    short8 o;
    o[0]=(short)f2bf(v0.x); o[1]=(short)f2bf(v0.y); o[2]=(short)f2bf(v0.z); o[3]=(short)f2bf(v0.w);
    o[4]=(short)f2bf(v1.x); o[5]=(short)f2bf(v1.y); o[6]=(short)f2bf(v1.z); o[7]=(short)f2bf(v1.w);
    *(short8*)(xb+i) = o;
  }
}

__global__ void cvt_w_kernel(const int* __restrict__ q, const float* __restrict__ scale,
                             const float* __restrict__ zp, ushort_t* __restrict__ wb){
  const int TOT = 45088768/8;
  for (int c = blockIdx.x*blockDim.x + threadIdx.x; c < TOT; c += gridDim.x*blockDim.x){
    int row = c >> 9;
    float s = scale[row];
    float b = -zp[row]*s;
    size_t i = (size_t)c*8;
    int4 q0 = *(const int4*)(q+i);
    int4 q1 = *(const int4*)(q+i+4);
    short8 o;
    o[0]=(short)f2bf((float)q0.x*s+b); o[1]=(short)f2bf((float)q0.y*s+b);
    o[2]=(short)f2bf((float)q0.z*s+b); o[3]=(short)f2bf((float)q0.w*s+b);
    o[4]=(short)f2bf((float)q1.x*s+b); o[5]=(short)f2bf((float)q1.y*s+b);
    o[6]=(short)f2bf((float)q1.z*s+b); o[7]=(short)f2bf((float)q1.w*s+b);
    *(short8*)(wb+i) = o;
  }
}

// ====== 256x256 GEMM, 32x32x16 MFMA, 4-buffer LDS, counted vmcnt (r8) ======
// r7 bug fixed: STAGE LDS destination stride was (2w+c)*1024 ushorts; the
// 16row x 32elem chunk is 512 ushorts, so waves 4-7 wrote out of bounds and
// rows >=128 of every tile were never staged (NaN from stale LDS). Correct
// base: (2w+c)*512 (lane l -> base+8l = row(l>>2)*32 + slot(l&3)*8).
// Also hardened: in-loop wait is now vmcnt(8)+lgkmcnt(0) — lgkm drain before
// the barrier closes the WAR window (reads issued ~8 MFMAs earlier: free).
// T4 intact: vmcnt never drains to 0 in the loop; depth-3 prefetch.
// Tail enumerated: kt=125 vmcnt(4), kt=126 vmcnt(0), kt=127 none.
// Swizzle (64B rows): LDS[row][s] = G[row][s ^ ((row>>1)&3)], s = 16B slot;
// read slot = (2KS+kx) ^ ((rl31>>1)&3): every 8-lane sweep hits 8 distinct
// bank-quads.

#define BAR() do{ asm volatile("" ::: "memory"); \
  __builtin_amdgcn_s_barrier(); \
  asm volatile("" ::: "memory"); }while(0)

#define VMWL(N) do{ __builtin_amdgcn_sched_barrier(0); \
  asm volatile("s_waitcnt vmcnt(" #N ") lgkmcnt(0)" ::: "memory"); \
  __builtin_amdgcn_sched_barrier(0); }while(0)

#define LOADSL(SLA, SLB, BUF, KS) do{ \
  const int _s = (((2*(KS)) + kx) ^ key) * 8; \
  const ushort_t* _a = &As[BUF][aRow*32 + _s]; \
  SLA[0] = *(const bf16x8*)(_a); \
  SLA[1] = *(const bf16x8*)(_a + 1024); \
  SLA[2] = *(const bf16x8*)(_a + 2048); \
  SLA[3] = *(const bf16x8*)(_a + 3072); \
  const ushort_t* _bp = &Bs[BUF][bRow*32 + _s]; \
  SLB[0] = *(const bf16x8*)(_bp); \
  SLB[1] = *(const bf16x8*)(_bp + 1024); \
}while(0)

#define MM(SLA, SLB) do{ \
  __builtin_amdgcn_s_setprio(1); \
  _Pragma("unroll") for (int mf=0; mf<4; ++mf) \
    _Pragma("unroll") for (int nf=0; nf<2; ++nf) \
      acc[mf][nf] = __builtin_amdgcn_mfma_f32_32x32x16_bf16( \
          SLA[mf], SLB[nf], acc[mf][nf], 0, 0, 0); \
  __builtin_amdgcn_s_setprio(0); \
}while(0)

#define STAGE(T) do{ const int _bf = (T)&3; \
  gll16(aSrc[0] + (size_t)(T)*32, &As[_bf][(2*w+0)*512]); \
  gll16(aSrc[1] + (size_t)(T)*32, &As[_bf][(2*w+1)*512]); \
  gll16(bSrc[0] + (size_t)(T)*32, &Bs[_bf][(2*w+0)*512]); \
  gll16(bSrc[1] + (size_t)(T)*32, &Bs[_bf][(2*w+1)*512]); \
}while(0)

__global__ __launch_bounds__(512, 2)
void qgemm256(const ushort_t* __restrict__ Xb, const ushort_t* __restrict__ Wb,
              const float* __restrict__ g_bias, float* __restrict__ Y)
{
  __shared__ __align__(16) ushort_t As[4][8192];   // 4 x 16 KB
  __shared__ __align__(16) ushort_t Bs[4][8192];   // 4 x 16 KB

  const int t    = threadIdx.x;
  const int lane = t & 63;
  const int w    = __builtin_amdgcn_readfirstlane(t >> 6);  // 0..7
  const int wm   = w >> 2;        // 0..1  (M half: 128 rows)
  const int wn   = w & 3;         // 0..3  (N quarter: 64 cols)

  const int GM2 = M_DIM/256, GN2 = N_DIM/256;    // 32, 43
  const int NWG2 = GM2*GN2;                      // 1376 (%8==0)
  int bid = blockIdx.x;
  int swz = (bid & 7) * (NWG2/8) + (bid >> 3);
  int by = swz / GN2, bx = swz - by*GN2;
  const int brow = by*256, bcol = bx*256;

  // lane constants
  const int rl31 = lane & 31;
  const int kx   = lane >> 5;           // k-half selector (0/1)
  const int key  = (rl31 >> 1) & 3;     // 64B-row swizzle key
  const int aRow = wm*128 + rl31;       // A LDS row base (+ mf*32 via imm)
  const int bRow = wn*64  + rl31;       // B LDS row base (+ nf*32 via imm)

  // staging: chunk = 16 rows x 32 elems (512 ush = 1KB); wave w owns chunks
  // 2w, 2w+1 of A and of B per tile. lane -> (row = l>>2, slot = l&3), source
  // pre-swizzled so LDS lands swizzled.
  const int g_r = lane >> 2;                       // 0..15
  const int g_s = (lane & 3) ^ ((lane >> 3) & 3);  // slot ^ (row>>1)&3
  const ushort_t* aSrc[2];
  const ushort_t* bSrc[2];
  #pragma unroll
  for (int c=0;c<2;++c){
    int r = 32*w + 16*c + g_r;
    aSrc[c] = Xb + (size_t)(brow + r)*K_DIM + g_s*8;
    bSrc[c] = Wb + (size_t)(bcol + r)*K_DIM + g_s*8;
  }

  f32x16 acc[4][2] = {};
  bf16x8 aX[4], aY[4];
  bf16x8 bX[2], bY[2];

  // ---- prologue: prefetch tiles 0,1,2 ----
  STAGE(0); STAGE(1); STAGE(2);
  VMWL(8);                   // retire tile 0's 4 stages; 8 stay in flight
  BAR();
  LOADSL(aX, bX, 0, 0);

  #pragma unroll 1
  for (int kt=0; kt<NT32-3; ++kt){      // kt = 0..124
    const int cur = kt & 3, nxt = (kt+1) & 3;
    STAGE(kt+3);
    LOADSL(aY, bY, cur, 1);  MM(aX, bX);
    VMWL(8);                            // retire tile kt+1's stages exactly
    BAR();
    LOADSL(aX, bX, nxt, 0);  MM(aY, bY);
  }
  // kt = 125 (buf 1): no stage left; outstanding = tiles 126,127 (8 ops)
  LOADSL(aY, bY, 1, 1);  MM(aX, bX);
  VMWL(4);                              // retire tile 126
  BAR();
  LOADSL(aX, bX, 2, 0);  MM(aY, bY);
  // kt = 126 (buf 2): outstanding = tile 127 (4 ops)
  LOADSL(aY, bY, 2, 1);  MM(aX, bX);
  VMWL(0);                              // retire tile 127 (once per block)
  BAR();
  LOADSL(aX, bX, 3, 0);  MM(aY, bY);
  // kt = 127 (buf 3)
  LOADSL(aY, bY, 3, 1);  MM(aX, bX);
  MM(aY, bY);

  // ---- epilogue: 32x32 C/D layout col=lane&31, row=(r&3)+8*(r>>2)+4*kx ----
  #pragma unroll
  for (int nf=0; nf<2; ++nf){
    const int col = bcol + wn*64 + nf*32 + rl31;
    const float bvs = g_bias[col];
    #pragma unroll
    for (int mf=0; mf<4; ++mf){
      const int rbase = brow + wm*128 + mf*32 + 4*kx;
      #pragma unroll
      for (int r=0; r<16; ++r){
        int row = rbase + (r&3) + 8*(r>>2);
        Y[(size_t)row*N_DIM + col] = acc[mf][nf][r] + bvs;
      }
    }
  }
}

// ============== fallback 128x128 dbuf GEMM (paths B/C, proven r2) ==============
template<bool PRE_A, bool PRE_B>
__global__ __launch_bounds__(256, 2)
void qgemm(const ushort_t* __restrict__ Xb, const float* __restrict__ Xf,
           const ushort_t* __restrict__ Wb, const int* __restrict__ Wq,
           const float* __restrict__ g_scale, const float* __restrict__ g_zp,
           const float* __restrict__ g_bias, float* __restrict__ Y)
{
  const int BM=128, BK=64, NT=K_DIM/BK, GRID_N=N_DIM/128, NWG=(M_DIM/128)*GRID_N;
  __shared__ __align__(16) ushort_t As[2][BM*BK];
  __shared__ __align__(16) ushort_t Bs[2][BM*BK];

  const int t = threadIdx.x, lane = t & 63, w = t >> 6;
  const int wr = w >> 1, wc = w & 1;
  int bid = blockIdx.x;
  int swz = (bid & 7) * (NWG/8) + (bid >> 3);
  int by = swz / GRID_N, bx = swz - by*GRID_N;
  const int brow = by*128, bcol = bx*128;

  f32x4 acc[4][4] = {};
  const int s8 = t & 7, r0 = t >> 3;
  const int g_r = lane >> 3, g_s = (lane & 7) ^ g_r;

  float wsc[4], wof[4];
  if constexpr (!PRE_B){
    #pragma unroll
    for (int i=0;i<4;++i){
      int n = bcol + r0 + 32*i;
      float sc = g_scale[n];
      wsc[i] = sc; wof[i] = -g_zp[n]*sc;
    }
  }
  float4 ax[4][2]; int4 bq[4][2];
  auto loadA = [&](int kt){
    #pragma unroll
    for (int i=0;i<4;++i){
      const float* p = Xf + (size_t)(brow + r0 + 32*i)*K_DIM + kt*BK + s8*8;
      ax[i][0] = *(const float4*)p; ax[i][1] = *(const float4*)(p+4);
    }};
  auto loadB = [&](int kt){
    #pragma unroll
    for (int i=0;i<4;++i){
      const int* p = Wq + (size_t)(bcol + r0 + 32*i)*K_DIM + kt*BK + s8*8;
      bq[i][0] = *(const int4*)p; bq[i][1] = *(const int4*)(p+4);
    }};
  auto stageA_gll = [&](int buf, int kt){
    #pragma unroll
    for (int i=0;i<4;++i){ int c = w*4 + i;
      gll16(Xb + (size_t)(brow + 8*c + g_r)*K_DIM + kt*BK + g_s*8, &As[buf][c*512]); }};
  auto stageB_gll = [&](int buf, int kt){
    #pragma unroll
    for (int i=0;i<4;++i){ int c = w*4 + i;
      gll16(Wb + (size_t)(bcol + 8*c + g_r)*K_DIM + kt*BK + g_s*8, &Bs[buf][c*512]); }};
  auto stageA_reg = [&](int buf){
    #pragma unroll
    for (int i=0;i<4;++i){
      short8 o;
      o[0]=(short)f2bf(ax[i][0].x); o[1]=(short)f2bf(ax[i][0].y);
      o[2]=(short)f2bf(ax[i][0].z); o[3]=(short)f2bf(ax[i][0].w);
      o[4]=(short)f2bf(ax[i][1].x); o[5]=(short)f2bf(ax[i][1].y);
      o[6]=(short)f2bf(ax[i][1].z); o[7]=(short)f2bf(ax[i][1].w);
      int r = r0 + 32*i; int idx = (r*BK + s8*8) ^ ((r&7)<<3);
      *(short8*)&As[buf][idx] = o; }};
  auto stageB_reg = [&](int buf){
    #pragma unroll
    for (int i=0;i<4;++i){
      short8 o;
      o[0]=(short)f2bf((float)bq[i][0].x*wsc[i]+wof[i]);
      o[1]=(short)f2bf((float)bq[i][0].y*wsc[i]+wof[i]);
      o[2]=(short)f2bf((float)bq[i][0].z*wsc[i]+wof[i]);
      o[3]=(short)f2bf((float)bq[i][0].w*wsc[i]+wof[i]);
      o[4]=(short)f2bf((float)bq[i][1].x*wsc[i]+wof[i]);
      o[5]=(short)f2bf((float)bq[i][1].y*wsc[i]+wof[i]);
      o[6]=(short)f2bf((float)bq[i][1].z*wsc[i]+wof[i]);
      o[7]=(short)f2bf((float)bq[i][1].w*wsc[i]+wof[i]);
      int r = r0 + 32*i; int idx = (r*BK + s8*8) ^ ((r&7)<<3);
      *(short8*)&Bs[buf][idx] = o; }};

  if constexpr (!PRE_A) loadA(0);
  if constexpr (!PRE_B) loadB(0);
  if constexpr (PRE_A) stageA_gll(0,0); else stageA_reg(0);
  if constexpr (PRE_B) stageB_gll(0,0); else stageB_reg(0);
  if constexpr (!PRE_A) { if (NT > 1) loadA(1); }
  if constexpr (!PRE_B) { if (NT > 1) loadB(1); }

  int cur = 0;
  for (int kt=0; kt<NT; ++kt){
    asm volatile("s_waitcnt vmcnt(0) lgkmcnt(0)" ::: "memory");
    __builtin_amdgcn_sched_barrier(0);
    __syncthreads();
    const int nxt = cur ^ 1;
    if (kt+1 < NT){
      if constexpr (PRE_A) stageA_gll(nxt, kt+1); else stageA_reg(nxt);
      if constexpr (PRE_B) stageB_gll(nxt, kt+1); else stageB_reg(nxt);
      if constexpr (!PRE_A) { if (kt+2 < NT) loadA(kt+2); }
      if constexpr (!PRE_B) { if (kt+2 < NT) loadB(kt+2); }
    }
    const ushort_t* as = As[cur];
    const ushort_t* bs = Bs[cur];
    #pragma unroll
    for (int kk=0; kk<2; ++kk){
      bf16x8 af[4], bfr[4];
      const int klo = kk*32 + ((lane>>4)<<3);
      #pragma unroll
      for (int mf=0; mf<4; ++mf){
        int r = wr*64 + mf*16 + (lane&15);
        af[mf] = *(const bf16x8*)&as[(r*BK + klo) ^ ((r&7)<<3)];
      }
      #pragma unroll
      for (int nf=0; nf<4; ++nf){
        int r = wc*64 + nf*16 + (lane&15);
        bfr[nf] = *(const bf16x8*)&bs[(r*BK + klo) ^ ((r&7)<<3)];
      }
      #pragma unroll
      for (int mf=0; mf<4; ++mf)
        #pragma unroll
        for (int nf=0; nf<4; ++nf)
          acc[mf][nf] = __builtin_amdgcn_mfma_f32_16x16x32_bf16(af[mf], bfr[nf], acc[mf][nf], 0,0,0);
    }
    cur = nxt;
  }
  const int cl = lane & 15, rq = (lane >> 4) << 2;
  #pragma unroll
  for (int nf=0; nf<4; ++nf){
    int col = bcol + wc*64 + nf*16 + cl;
    float bvs = g_bias[col];
    #pragma unroll
    for (int mf=0; mf<4; ++mf){
      int row = brow + wr*64 + mf*16 + rq;
      f32x4 v = acc[mf][nf];
      #pragma unroll
      for (int i=0;i<4;++i)
        Y[(size_t)(row+i)*N_DIM + col] = v[i] + bvs;
    }
  }
}

// ---------------- launch ----------------
extern "C" void kernel_launch(void* const* d_in, const int* in_sizes, int n_in,
                              void* d_out, int out_size, void* d_ws, size_t ws_size,
                              hipStream_t stream) {
  const float* x     = (const float*)d_in[0];
  const int*   qw    = (const int*)  d_in[1];
  const float* scale = (const float*)d_in[2];
  const float* zp    = (const float*)d_in[3];
  const float* bias  = (const float*)d_in[4];
  float* y = (float*)d_out;

  const size_t XB = (size_t)M_DIM*K_DIM*2;
  const size_t WB = (size_t)N_DIM*K_DIM*2;

  if (ws_size >= XB + WB){
    ushort_t* xb = (ushort_t*)d_ws;
    ushort_t* wb = (ushort_t*)((char*)d_ws + XB);
    cvt_x_kernel<<<2048, 256, 0, stream>>>(x, xb);
    cvt_w_kernel<<<2048, 256, 0, stream>>>(qw, scale, zp, wb);
    qgemm256<<<dim3((M_DIM/256)*(N_DIM/256)), dim3(512), 0, stream>>>(xb, wb, bias, y);
  } else if (ws_size >= WB){
    ushort_t* wb = (ushort_t*)d_ws;
    cvt_w_kernel<<<2048, 256, 0, stream>>>(qw, scale, zp, wb);
    qgemm<false,true><<<dim3((M_DIM/128)*(N_DIM/128)), dim3(256), 0, stream>>>(nullptr, x, wb, nullptr, scale, zp, bias, y);
  } else {
    qgemm<false,false><<<dim3((M_DIM/128)*(N_DIM/128)), dim3(256), 0, stream>>>(nullptr, x, nullptr, qw, scale, zp, bias, y);
  }
}

// Round 13
// 949.101 us; speedup vs baseline: 1.1239x; 1.1239x over previous
//
#include <hip/hip_runtime.h>
#include <hip/hip_bf16.h>
#include <stdint.h>

// ---------------- problem constants ----------------
#define M_DIM 8192            // B*S = 4*2048
#define N_DIM 11008
#define K_DIM 4096
#define NTILE 64              // K-tiles of 64

typedef unsigned short ushort_t;
typedef __attribute__((ext_vector_type(8))) short  short8;
typedef __attribute__((ext_vector_type(8))) __bf16 bf16x8;
typedef __attribute__((ext_vector_type(4))) float  f32x4;

__device__ __forceinline__ ushort_t f2bf(float f){
  uint32_t u = __builtin_bit_cast(uint32_t, f);
  u += 0x7FFFu + ((u >> 16) & 1u);
  return (ushort_t)(u >> 16);
}

__device__ __forceinline__ void gll16(const void* g, void* l){
  __builtin_amdgcn_global_load_lds(
      (const __attribute__((address_space(1))) void*)g,
      (__attribute__((address_space(3))) void*)l,
      16, 0, 0);
}

// ---------------- pre-pass converts ----------------
__global__ void cvt_x_kernel(const float* __restrict__ x, ushort_t* __restrict__ xb){
  const int TOT = 33554432/8;
  for (int c = blockIdx.x*blockDim.x + threadIdx.x; c < TOT; c += gridDim.x*blockDim.x){
    size_t i = (size_t)c*8;
    float4 v0 = *(const float4*)(x+i);
    float4 v1 = *(const float4*)(x+i+4);
    short8 o;
    o[0]=(short)f2bf(v0.x); o[1]=(short)f2bf(v0.y); o[2]=(short)f2bf(v0.z); o[3]=(short)f2bf(v0.w);
    o[4]=(short)f2bf(v1.x); o[5]=(short)f2bf(v1.y); o[6]=(short)f2bf(v1.z); o[7]=(short)f2bf(v1.w);
    *(short8*)(xb+i) = o;
  }
}

__global__ void cvt_w_kernel(const int* __restrict__ q, const float* __restrict__ scale,
                             const float* __restrict__ zp, ushort_t* __restrict__ wb){
  const int TOT = 45088768/8;
  for (int c = blockIdx.x*blockDim.x + threadIdx.x; c < TOT; c += gridDim.x*blockDim.x){
    int row = c >> 9;
    float s = scale[row];
    float b = -zp[row]*s;
    size_t i = (size_t)c*8;
    int4 q0 = *(const int4*)(q+i);
    int4 q1 = *(const int4*)(q+i+4);
    short8 o;
    o[0]=(short)f2bf((float)q0.x*s+b); o[1]=(short)f2bf((float)q0.y*s+b);
    o[2]=(short)f2bf((float)q0.z*s+b); o[3]=(short)f2bf((float)q0.w*s+b);
    o[4]=(short)f2bf((float)q1.x*s+b); o[5]=(short)f2bf((float)q1.y*s+b);
    o[6]=(short)f2bf((float)q1.z*s+b); o[7]=(short)f2bf((float)q1.w*s+b);
    *(short8*)(wb+i) = o;
  }
}

// ====== 256x256 8-phase GEMM, 16x16x32, reads-before-barrier (r9) ======
// m201 phase recipe verbatim: { ds_reads(p) || stage(p) } -> s_barrier ->
// lgkmcnt(0) -> setprio(1) 16xMFMA setprio(0) -> s_barrier. Read latency
// drains during barrier-sync skew instead of sitting exposed before MFMA
// (r3's 38.7% cause). Fragments single-buffered (r3 liveness, no r5 spill):
// afX=G0, afY=G1, bfX=N01... bfX=N0, bfY=N1; each reloaded only after last use.
// vmcnt discipline = r3's proof (re-verified with new windows):
//   ph4 vmcnt(4) retires {prev ph7, prev ph8, ph1, ph2} = all of buf1/t1;
//   ph8 vmcnt(4) retires {ph3..ph6} = all of buf0/t2; never 0 in the loop.
// Peeled tail (r5): last iteration's ph4 does vmcnt(0) (counted wait would
// under-retire when t2/t3 stages are absent — the r4 race).
// All read/stage pairs per window touch disjoint LDS (A vs B array, or
// buf0 vs buf1) — checked phase by phase.

#define BAR() do{ asm volatile("" ::: "memory"); \
  __builtin_amdgcn_s_barrier(); \
  asm volatile("" ::: "memory"); }while(0)

#define LGKM0() asm volatile("s_waitcnt lgkmcnt(0)" ::: "memory")

#define VMCNT4() do{ __builtin_amdgcn_sched_barrier(0); \
  asm volatile("s_waitcnt vmcnt(4)" ::: "memory"); \
  __builtin_amdgcn_sched_barrier(0); }while(0)

#define VMCNT0() do{ __builtin_amdgcn_sched_barrier(0); \
  asm volatile("s_waitcnt vmcnt(0)" ::: "memory"); \
  __builtin_amdgcn_sched_barrier(0); }while(0)

#define LDA_TO(DST, BUF, G) do{ \
  const ushort_t* _b = &As[BUF][wm][((G)*64 + rl)*64]; \
  _Pragma("unroll") for (int mf=0; mf<4; ++mf){ \
    DST[mf][0] = *(const bf16x8*)(_b + mf*1024 + offk0); \
    DST[mf][1] = *(const bf16x8*)(_b + mf*1024 + offk1); } \
}while(0)

#define LDB_TO(DST, BUF, NG) do{ \
  const ushort_t* _b = &Bs[BUF][hb][(hbr + (NG)*32 + rl)*64]; \
  _Pragma("unroll") for (int nfl=0; nfl<2; ++nfl){ \
    DST[nfl][0] = *(const bf16x8*)(_b + nfl*1024 + offk0); \
    DST[nfl][1] = *(const bf16x8*)(_b + nfl*1024 + offk1); } \
}while(0)

#define MFMA_Q(AF, BF, MG, NG) do{ \
  __builtin_amdgcn_s_setprio(1); \
  _Pragma("unroll") for (int mf=0; mf<4; ++mf) \
    _Pragma("unroll") for (int nfl=0; nfl<2; ++nfl) \
      _Pragma("unroll") for (int kk=0; kk<2; ++kk) \
        acc[(MG)*4+mf][(NG)*2+nfl] = __builtin_amdgcn_mfma_f32_16x16x32_bf16( \
            AF[mf][kk], BF[nfl][kk], acc[(MG)*4+mf][(NG)*2+nfl], 0,0,0); \
  __builtin_amdgcn_s_setprio(0); \
}while(0)

#define STAGE_A(BUF, H, T) do{ \
  gll16(aS[H][0] + (size_t)(T)*64, &As[BUF][H][w*1024]); \
  gll16(aS[H][1] + (size_t)(T)*64, &As[BUF][H][w*1024+512]); }while(0)

#define STAGE_B(BUF, H, T) do{ \
  gll16(bS[H][0] + (size_t)(T)*64, &Bs[BUF][H][w*1024]); \
  gll16(bS[H][1] + (size_t)(T)*64, &Bs[BUF][H][w*1024+512]); }while(0)

__global__ __launch_bounds__(512, 2)
void qgemm256(const ushort_t* __restrict__ Xb, const ushort_t* __restrict__ Wb,
              const float* __restrict__ g_bias, float* __restrict__ Y)
{
  __shared__ __align__(16) ushort_t As[2][2][8192];   // 64 KB
  __shared__ __align__(16) ushort_t Bs[2][2][8192];   // 64 KB

  const int t    = threadIdx.x;
  const int lane = t & 63;
  const int w    = t >> 6;        // 0..7
  const int wm   = w >> 2;        // 0..1  (M half)
  const int wn   = w & 3;         // 0..3  (N quarter)
  const int hb   = wn >> 1;       // B half
  const int hbr  = (wn & 1) * 64; // row base within B half

  const int GM2 = M_DIM/256, GN2 = N_DIM/256;   // 32, 43
  const int NWG2 = GM2*GN2;                      // 1376 (%8==0)
  int bid = blockIdx.x;
  int swz = (bid & 7) * (NWG2/8) + (bid >> 3);
  int by = swz / GN2, bx = swz - by*GN2;
  const int brow = by*256, bcol = bx*256;

  const int rl    = lane & 15;
  const int offk0 = (((lane>>4)    ) ^ (lane&7)) * 8;   // kk=0 (elements)
  const int offk1 = (((lane>>4) + 4) ^ (lane&7)) * 8;   // kk=1

  // staging geometry: wave w owns chunks 2w,2w+1 of each half-tile;
  // lane fetches pre-swizzled global slot so LDS lands XOR-swizzled.
  const int g_r = lane >> 3;
  const int g_s = (lane & 7) ^ g_r;
  const ushort_t* aS[2][2];
  const ushort_t* bS[2][2];
  #pragma unroll
  for (int h=0; h<2; ++h)
    #pragma unroll
    for (int ci=0; ci<2; ++ci){
      int r8 = 8*(2*w+ci) + g_r;
      aS[h][ci] = Xb + (size_t)(brow + h*128 + r8)*K_DIM + g_s*8;
      bS[h][ci] = Wb + (size_t)(bcol + h*128 + r8)*K_DIM + g_s*8;
    }

  f32x4 acc[8][4] = {};
  bf16x8 afX[4][2], afY[4][2];   // A fragments: G0 / G1
  bf16x8 bfX[2][2], bfY[2][2];   // B fragments: N0 / N1

  // ---- prologue: buf0 <- tile0 (4 halves), buf1 <- tile1 (B.h0, A.h0) ----
  STAGE_B(0,0,0); STAGE_A(0,0,0); STAGE_A(0,1,0); STAGE_B(0,1,0);
  STAGE_B(1,0,1); STAGE_A(1,0,1);
  VMCNT4();                 // retire buf0's 4 halves; buf1's 2 stay in flight
  BAR();

  #pragma unroll 1
  for (int j=0; j<NTILE/2-1; ++j){      // j = 0..30
    const int t1 = 2*j+1, t2 = 2*j+2, t3 = 2*j+3;
    // ph1: reads Q(0,0)@buf0 | stage A[b1].h1 <- t1
    LDA_TO(afX, 0, 0);
    LDB_TO(bfX, 0, 0);
    STAGE_A(1,1,t1);
    BAR(); LGKM0();
    MFMA_Q(afX, bfX, 0, 0);
    BAR();
    // ph2: reads B.N1@buf0 | stage B[b1].h1 <- t1
    LDB_TO(bfY, 0, 1);
    STAGE_B(1,1,t1);
    BAR(); LGKM0();
    MFMA_Q(afX, bfY, 0, 1);
    BAR();
    // ph3: reads A.G1@buf0 | stage B[b0].h0 <- t2
    LDA_TO(afY, 0, 1);
    STAGE_B(0,0,t2);
    BAR(); LGKM0();
    MFMA_Q(afY, bfX, 1, 0);
    BAR();
    // ph4: no reads | stage A[b0].h0 <- t2 | vmcnt(4): buf1/t1 published
    STAGE_A(0,0,t2);
    VMCNT4();
    BAR();
    MFMA_Q(afY, bfY, 1, 1);
    BAR();
    // ph5: reads Q(0,0)@buf1 | stage A[b0].h1 <- t2
    LDA_TO(afX, 1, 0);
    LDB_TO(bfX, 1, 0);
    STAGE_A(0,1,t2);
    BAR(); LGKM0();
    MFMA_Q(afX, bfX, 0, 0);
    BAR();
    // ph6: reads B.N1@buf1 | stage B[b0].h1 <- t2
    LDB_TO(bfY, 1, 1);
    STAGE_B(0,1,t2);
    BAR(); LGKM0();
    MFMA_Q(afX, bfY, 0, 1);
    BAR();
    // ph7: reads A.G1@buf1 | stage B[b1].h0 <- t3
    LDA_TO(afY, 1, 1);
    STAGE_B(1,0,t3);
    BAR(); LGKM0();
    MFMA_Q(afY, bfX, 1, 0);
    BAR();
    // ph8: no reads | stage A[b1].h0 <- t3 | vmcnt(4): buf0/t2 published
    STAGE_A(1,0,t3);
    VMCNT4();
    BAR();
    MFMA_Q(afY, bfY, 1, 1);
    BAR();
  }

  // ---- peeled tail (tiles 62,63): ph4 full-drains (r4 race fix) ----
  {
    const int t1 = NTILE-1;   // 63
    // ph1
    LDA_TO(afX, 0, 0);
    LDB_TO(bfX, 0, 0);
    STAGE_A(1,1,t1);
    BAR(); LGKM0();
    MFMA_Q(afX, bfX, 0, 0);
    BAR();
    // ph2
    LDB_TO(bfY, 0, 1);
    STAGE_B(1,1,t1);
    BAR(); LGKM0();
    MFMA_Q(afX, bfY, 0, 1);
    BAR();
    // ph3
    LDA_TO(afY, 0, 1);
    BAR(); LGKM0();
    MFMA_Q(afY, bfX, 1, 0);
    BAR();
    // ph4: FULL drain -> all of buf1/t63 published
    VMCNT0();
    BAR();
    MFMA_Q(afY, bfY, 1, 1);
    BAR();
    // ph5
    LDA_TO(afX, 1, 0);
    LDB_TO(bfX, 1, 0);
    BAR(); LGKM0();
    MFMA_Q(afX, bfX, 0, 0);
    BAR();
    // ph6
    LDB_TO(bfY, 1, 1);
    BAR(); LGKM0();
    MFMA_Q(afX, bfY, 0, 1);
    BAR();
    // ph7
    LDA_TO(afY, 1, 1);
    BAR(); LGKM0();
    MFMA_Q(afY, bfX, 1, 0);
    BAR();
    // ph8
    MFMA_Q(afY, bfY, 1, 1);
  }

  // ---- epilogue: C/D layout col=lane&15, row=(lane>>4)*4+i ----
  const int cl = lane & 15;
  const int rq = (lane >> 4) << 2;
  #pragma unroll
  for (int nf=0; nf<4; ++nf){
    int col = bcol + wn*64 + nf*16 + cl;
    float bvs = g_bias[col];
    #pragma unroll
    for (int mf=0; mf<8; ++mf){
      int row = brow + wm*128 + mf*16 + rq;
      f32x4 v = acc[mf][nf];
      #pragma unroll
      for (int i=0;i<4;++i)
        Y[(size_t)(row+i)*N_DIM + col] = v[i] + bvs;
    }
  }
}

// ============== fallback 128x128 dbuf GEMM (paths B/C, proven r2) ==============
template<bool PRE_A, bool PRE_B>
__global__ __launch_bounds__(256, 2)
void qgemm(const ushort_t* __restrict__ Xb, const float* __restrict__ Xf,
           const ushort_t* __restrict__ Wb, const int* __restrict__ Wq,
           const float* __restrict__ g_scale, const float* __restrict__ g_zp,
           const float* __restrict__ g_bias, float* __restrict__ Y)
{
  const int BM=128, BK=64, NT=K_DIM/BK, GRID_N=N_DIM/128, NWG=(M_DIM/128)*GRID_N;
  __shared__ __align__(16) ushort_t As[2][BM*BK];
  __shared__ __align__(16) ushort_t Bs[2][BM*BK];

  const int t = threadIdx.x, lane = t & 63, w = t >> 6;
  const int wr = w >> 1, wc = w & 1;
  int bid = blockIdx.x;
  int swz = (bid & 7) * (NWG/8) + (bid >> 3);
  int by = swz / GRID_N, bx = swz - by*GRID_N;
  const int brow = by*128, bcol = bx*128;

  f32x4 acc[4][4] = {};
  const int s8 = t & 7, r0 = t >> 3;
  const int g_r = lane >> 3, g_s = (lane & 7) ^ g_r;

  float wsc[4], wof[4];
  if constexpr (!PRE_B){
    #pragma unroll
    for (int i=0;i<4;++i){
      int n = bcol + r0 + 32*i;
      float sc = g_scale[n];
      wsc[i] = sc; wof[i] = -g_zp[n]*sc;
    }
  }
  float4 ax[4][2]; int4 bq[4][2];
  auto loadA = [&](int kt){
    #pragma unroll
    for (int i=0;i<4;++i){
      const float* p = Xf + (size_t)(brow + r0 + 32*i)*K_DIM + kt*BK + s8*8;
      ax[i][0] = *(const float4*)p; ax[i][1] = *(const float4*)(p+4);
    }};
  auto loadB = [&](int kt){
    #pragma unroll
    for (int i=0;i<4;++i){
      const int* p = Wq + (size_t)(bcol + r0 + 32*i)*K_DIM + kt*BK + s8*8;
      bq[i][0] = *(const int4*)p; bq[i][1] = *(const int4*)(p+4);
    }};
  auto stageA_gll = [&](int buf, int kt){
    #pragma unroll
    for (int i=0;i<4;++i){ int c = w*4 + i;
      gll16(Xb + (size_t)(brow + 8*c + g_r)*K_DIM + kt*BK + g_s*8, &As[buf][c*512]); }};
  auto stageB_gll = [&](int buf, int kt){
    #pragma unroll
    for (int i=0;i<4;++i){ int c = w*4 + i;
      gll16(Wb + (size_t)(bcol + 8*c + g_r)*K_DIM + kt*BK + g_s*8, &Bs[buf][c*512]); }};
  auto stageA_reg = [&](int buf){
    #pragma unroll
    for (int i=0;i<4;++i){
      short8 o;
      o[0]=(short)f2bf(ax[i][0].x); o[1]=(short)f2bf(ax[i][0].y);
      o[2]=(short)f2bf(ax[i][0].z); o[3]=(short)f2bf(ax[i][0].w);
      o[4]=(short)f2bf(ax[i][1].x); o[5]=(short)f2bf(ax[i][1].y);
      o[6]=(short)f2bf(ax[i][1].z); o[7]=(short)f2bf(ax[i][1].w);
      int r = r0 + 32*i; int idx = (r*BK + s8*8) ^ ((r&7)<<3);
      *(short8*)&As[buf][idx] = o; }};
  auto stageB_reg = [&](int buf){
    #pragma unroll
    for (int i=0;i<4;++i){
      short8 o;
      o[0]=(short)f2bf((float)bq[i][0].x*wsc[i]+wof[i]);
      o[1]=(short)f2bf((float)bq[i][0].y*wsc[i]+wof[i]);
      o[2]=(short)f2bf((float)bq[i][0].z*wsc[i]+wof[i]);
      o[3]=(short)f2bf((float)bq[i][0].w*wsc[i]+wof[i]);
      o[4]=(short)f2bf((float)bq[i][1].x*wsc[i]+wof[i]);
      o[5]=(short)f2bf((float)bq[i][1].y*wsc[i]+wof[i]);
      o[6]=(short)f2bf((float)bq[i][1].z*wsc[i]+wof[i]);
      o[7]=(short)f2bf((float)bq[i][1].w*wsc[i]+wof[i]);
      int r = r0 + 32*i; int idx = (r*BK + s8*8) ^ ((r&7)<<3);
      *(short8*)&Bs[buf][idx] = o; }};

  if constexpr (!PRE_A) loadA(0);
  if constexpr (!PRE_B) loadB(0);
  if constexpr (PRE_A) stageA_gll(0,0); else stageA_reg(0);
  if constexpr (PRE_B) stageB_gll(0,0); else stageB_reg(0);
  if constexpr (!PRE_A) { if (NT > 1) loadA(1); }
  if constexpr (!PRE_B) { if (NT > 1) loadB(1); }

  int cur = 0;
  for (int kt=0; kt<NT; ++kt){
    asm volatile("s_waitcnt vmcnt(0) lgkmcnt(0)" ::: "memory");
    __builtin_amdgcn_sched_barrier(0);
    __syncthreads();
    const int nxt = cur ^ 1;
    if (kt+1 < NT){
      if constexpr (PRE_A) stageA_gll(nxt, kt+1); else stageA_reg(nxt);
      if constexpr (PRE_B) stageB_gll(nxt, kt+1); else stageB_reg(nxt);
      if constexpr (!PRE_A) { if (kt+2 < NT) loadA(kt+2); }
      if constexpr (!PRE_B) { if (kt+2 < NT) loadB(kt+2); }
    }
    const ushort_t* as = As[cur];
    const ushort_t* bs = Bs[cur];
    #pragma unroll
    for (int kk=0; kk<2; ++kk){
      bf16x8 af[4], bfr[4];
      const int klo = kk*32 + ((lane>>4)<<3);
      #pragma unroll
      for (int mf=0; mf<4; ++mf){
        int r = wr*64 + mf*16 + (lane&15);
        af[mf] = *(const bf16x8*)&as[(r*BK + klo) ^ ((r&7)<<3)];
      }
      #pragma unroll
      for (int nf=0; nf<4; ++nf){
        int r = wc*64 + nf*16 + (lane&15);
        bfr[nf] = *(const bf16x8*)&bs[(r*BK + klo) ^ ((r&7)<<3)];
      }
      #pragma unroll
      for (int mf=0; mf<4; ++mf)
        #pragma unroll
        for (int nf=0; nf<4; ++nf)
          acc[mf][nf] = __builtin_amdgcn_mfma_f32_16x16x32_bf16(af[mf], bfr[nf], acc[mf][nf], 0,0,0);
    }
    cur = nxt;
  }
  const int cl = lane & 15, rq = (lane >> 4) << 2;
  #pragma unroll
  for (int nf=0; nf<4; ++nf){
    int col = bcol + wc*64 + nf*16 + cl;
    float bvs = g_bias[col];
    #pragma unroll
    for (int mf=0; mf<4; ++mf){
      int row = brow + wr*64 + mf*16 + rq;
      f32x4 v = acc[mf][nf];
      #pragma unroll
      for (int i=0;i<4;++i)
        Y[(size_t)(row+i)*N_DIM + col] = v[i] + bvs;
    }
  }
}

// ---------------- launch ----------------
extern "C" void kernel_launch(void* const* d_in, const int* in_sizes, int n_in,
                              void* d_out, int out_size, void* d_ws, size_t ws_size,
                              hipStream_t stream) {
  const float* x     = (const float*)d_in[0];
  const int*   qw    = (const int*)  d_in[1];
  const float* scale = (const float*)d_in[2];
  const float* zp    = (const float*)d_in[3];
  const float* bias  = (const float*)d_in[4];
  float* y = (float*)d_out;

  const size_t XB = (size_t)M_DIM*K_DIM*2;
  const size_t WB = (size_t)N_DIM*K_DIM*2;

  if (ws_size >= XB + WB){
    ushort_t* xb = (ushort_t*)d_ws;
    ushort_t* wb = (ushort_t*)((char*)d_ws + XB);
    cvt_x_kernel<<<2048, 256, 0, stream>>>(x, xb);
    cvt_w_kernel<<<2048, 256, 0, stream>>>(qw, scale, zp, wb);
    qgemm256<<<dim3((M_DIM/256)*(N_DIM/256)), dim3(512), 0, stream>>>(xb, wb, bias, y);
  } else if (ws_size >= WB){
    ushort_t* wb = (ushort_t*)d_ws;
    cvt_w_kernel<<<2048, 256, 0, stream>>>(qw, scale, zp, wb);
    qgemm<false,true><<<dim3((M_DIM/128)*(N_DIM/128)), dim3(256), 0, stream>>>(nullptr, x, wb, nullptr, scale, zp, bias, y);
  } else {
    qgemm<false,false><<<dim3((M_DIM/128)*(N_DIM/128)), dim3(256), 0, stream>>>(nullptr, x, nullptr, qw, scale, zp, bias, y);
  }
}